// Round 6
// baseline (358.206 us; speedup 1.0000x reference)
//
#include <hip/hip_runtime.h>
#include <math.h>

#define TT    512
#define BB    512
#define HID   32
#define EMB   32
#define FFD   16
#define NCLS  7
#define VOCABN 1000

typedef float v2f __attribute__((ext_vector_type(2)));
typedef float v4f __attribute__((ext_vector_type(4)));

#define NLOG2E  (-1.4426950408889634f)
#define N2LOG2E (-2.8853900817779268f)

__device__ __forceinline__ float rl(float v, int k) {
    return __int_as_float(__builtin_amdgcn_readlane(__float_as_int(v), k));
}
__device__ __forceinline__ float fast_rcp(float x) {
#if defined(__has_builtin)
#if __has_builtin(__builtin_amdgcn_rcpf)
    return __builtin_amdgcn_rcpf(x);
#else
    return 1.0f / x;
#endif
#else
    return 1.0f / x;
#endif
}
__device__ __forceinline__ float sigf(float x) { return fast_rcp(1.0f + __expf(-x)); }
__device__ __forceinline__ float tanh_fast(float x) { return 2.0f * sigf(2.0f * x) - 1.0f; }

__device__ __forceinline__ v2f fma2(v2f a, v2f b, v2f c) {
#if defined(__has_builtin)
#if __has_builtin(__builtin_elementwise_fma)
    return __builtin_elementwise_fma(a, b, c);
#else
    v2f r; r.x = fmaf(a.x, b.x, c.x); r.y = fmaf(a.y, b.y, c.y); return r;
#endif
#else
    v2f r; r.x = fmaf(a.x, b.x, c.x); r.y = fmaf(a.y, b.y, c.y); return r;
#endif
}

// Cross-half (lane ^ 32) exchange via v_permlane32_swap_b32 (VALU) instead of
// ds_permute-based __shfl_xor. Orientation-proof: r[0]^r[1]^self == partner.
__device__ __forceinline__ float xhalf_swap(float v) {
#if defined(__has_builtin)
#if __has_builtin(__builtin_amdgcn_permlane32_swap)
    const unsigned u = __float_as_uint(v);
    auto r = __builtin_amdgcn_permlane32_swap(u, u, false, false);
    return __uint_as_float((r[0] ^ r[1]) ^ u);
#else
    return __shfl_xor(v, 32);
#endif
#else
    return __shfl_xor(v, 32);
#endif
}

// xg_table[v][j] = {W_ih[j,:]·emb[v,:]+b[j], W_ih[j+64,:]·emb[v,:]+b[j+64]}
// scaled!=0: entries pre-multiplied by the activation log2-scales (see lstm_rec2).
__global__ __launch_bounds__(64) void build_xg(
    const float* __restrict__ emb, const float* __restrict__ W_ih,
    const float* __restrict__ b_ih, const float* __restrict__ b_hh,
    float2* __restrict__ tab, int scaled)
{
    const int v = blockIdx.x;
    const int j = threadIdx.x;
    const float* e  = emb + v * EMB;
    const float* w0 = W_ih + j * EMB;
    const float* w1 = W_ih + (j + 64) * EMB;
    float a0 = b_ih[j]      + b_hh[j];
    float a1 = b_ih[j + 64] + b_hh[j + 64];
    #pragma unroll
    for (int k = 0; k < EMB; ++k) {
        const float ek = e[k];
        a0 = fmaf(w0[k], ek, a0);
        a1 = fmaf(w1[k], ek, a1);
    }
    float s0 = 1.0f, s1 = 1.0f;
    if (scaled) { s0 = NLOG2E; s1 = (j < 32) ? N2LOG2E : NLOG2E; }
    tab[v * 64 + j] = make_float2(a0 * s0, a1 * s1);
}

// Serial recurrence. ROUND-5 EVIDENCE: per-step 689 cyc, issue ~180 cyc ->
// ~500 cyc of dependence-chain stall that survived broadcast-mechanism and
// instruction-count changes. With ONE wave per SIMD nothing fills the gaps
// (Occupancy 5.7%). Fix: TWO independent chains per wave (grid BB/2). The two
// chains' instruction DAGs are independent -> the scheduler interleaves them,
// chain-1 issues inside chain-0's stalls. Weights shared (register-resident,
// VGPR 132 proved in R4/R5); per-chain LDS staging buffers; unconditional
// staging write (lanes m, m+32 hold identical h -> benign same-addr dup).
__global__ __launch_bounds__(64)
__attribute__((amdgpu_waves_per_eu(1, 1)))
void lstm_rec2(
    const int* __restrict__ x, const float2* __restrict__ tab,
    const float* __restrict__ W_hh, float* __restrict__ hsout)
{
    const int b0 = blockIdx.x * 2;
    const int b1 = b0 + 1;
    const int j  = threadIdx.x;
    const int m  = j & 31;
    const bool lo = j < 32;

    __shared__ __align__(16) float sh0[8 * HID];
    __shared__ __align__(16) float sh1[8 * HID];

    // ---- W_hh rows j, j+64 -> 32 named v2f pairs, pre-scaled (shared) ----
    const float fA = NLOG2E;
    const float fB = lo ? N2LOG2E : NLOG2E;
    const v2f sA2 = {fA, fA};
    const v2f sB2 = {fB, fB};
    const v4f* WA = (const v4f*)(W_hh + j * HID);
    const v4f* WB = (const v4f*)(W_hh + (j + 64) * HID);
    v4f t;
    v2f wpa0,wpa1,wpa2,wpa3,wpa4,wpa5,wpa6,wpa7,wpa8,wpa9,wpa10,wpa11,wpa12,wpa13,wpa14,wpa15;
    v2f wpb0,wpb1,wpb2,wpb3,wpb4,wpb5,wpb6,wpb7,wpb8,wpb9,wpb10,wpb11,wpb12,wpb13,wpb14,wpb15;
    t = WA[0]; wpa0  = t.lo * sA2; wpa1  = t.hi * sA2;
    t = WA[1]; wpa2  = t.lo * sA2; wpa3  = t.hi * sA2;
    t = WA[2]; wpa4  = t.lo * sA2; wpa5  = t.hi * sA2;
    t = WA[3]; wpa6  = t.lo * sA2; wpa7  = t.hi * sA2;
    t = WA[4]; wpa8  = t.lo * sA2; wpa9  = t.hi * sA2;
    t = WA[5]; wpa10 = t.lo * sA2; wpa11 = t.hi * sA2;
    t = WA[6]; wpa12 = t.lo * sA2; wpa13 = t.hi * sA2;
    t = WA[7]; wpa14 = t.lo * sA2; wpa15 = t.hi * sA2;
    t = WB[0]; wpb0  = t.lo * sB2; wpb1  = t.hi * sB2;
    t = WB[1]; wpb2  = t.lo * sB2; wpb3  = t.hi * sB2;
    t = WB[2]; wpb4  = t.lo * sB2; wpb5  = t.hi * sB2;
    t = WB[3]; wpb6  = t.lo * sB2; wpb7  = t.hi * sB2;
    t = WB[4]; wpb8  = t.lo * sB2; wpb9  = t.hi * sB2;
    t = WB[5]; wpb10 = t.lo * sB2; wpb11 = t.hi * sB2;
    t = WB[6]; wpb12 = t.lo * sB2; wpb13 = t.hi * sB2;
    t = WB[7]; wpb14 = t.lo * sB2; wpb15 = t.hi * sB2;

    float c0 = 0.f, c1 = 0.f;
    float* hrow0 = hsout + (size_t)b0 * TT * HID;
    float* hrow1 = hsout + (size_t)b1 * TT * HID;

    // broadcast source slot 7 = "previous h"; zero for t=0
    sh0[7 * HID + m] = 0.0f;
    sh1[7 * HID + m] = 0.0f;

    // one LSTM step for one chain; everything else is shared
    auto dostep = [&](int u, float* shc, const float2 xgv, float& cc) {
        const float* hb = shc + ((u + 7) & 7) * HID;
        const v4f h0 = *(const v4f*)(hb + 0);
        const v4f h1 = *(const v4f*)(hb + 4);
        const v4f h2 = *(const v4f*)(hb + 8);
        const v4f h3 = *(const v4f*)(hb + 12);
        const v4f h4 = *(const v4f*)(hb + 16);
        const v4f h5 = *(const v4f*)(hb + 20);
        const v4f h6 = *(const v4f*)(hb + 24);
        const v4f h7 = *(const v4f*)(hb + 28);

        v2f aP0 = {xgv.x, 0.f}, aP1 = {0.f, 0.f};
        v2f aQ0 = {xgv.y, 0.f}, aQ1 = {0.f, 0.f};
        aP0 = fma2(wpa0,  h0.lo, aP0);  aP1 = fma2(wpa1,  h0.hi, aP1);
        aQ0 = fma2(wpb0,  h0.lo, aQ0);  aQ1 = fma2(wpb1,  h0.hi, aQ1);
        aP0 = fma2(wpa2,  h1.lo, aP0);  aP1 = fma2(wpa3,  h1.hi, aP1);
        aQ0 = fma2(wpb2,  h1.lo, aQ0);  aQ1 = fma2(wpb3,  h1.hi, aQ1);
        aP0 = fma2(wpa4,  h2.lo, aP0);  aP1 = fma2(wpa5,  h2.hi, aP1);
        aQ0 = fma2(wpb4,  h2.lo, aQ0);  aQ1 = fma2(wpb5,  h2.hi, aQ1);
        aP0 = fma2(wpa6,  h3.lo, aP0);  aP1 = fma2(wpa7,  h3.hi, aP1);
        aQ0 = fma2(wpb6,  h3.lo, aQ0);  aQ1 = fma2(wpb7,  h3.hi, aQ1);
        aP0 = fma2(wpa8,  h4.lo, aP0);  aP1 = fma2(wpa9,  h4.hi, aP1);
        aQ0 = fma2(wpb8,  h4.lo, aQ0);  aQ1 = fma2(wpb9,  h4.hi, aQ1);
        aP0 = fma2(wpa10, h5.lo, aP0);  aP1 = fma2(wpa11, h5.hi, aP1);
        aQ0 = fma2(wpb10, h5.lo, aQ0);  aQ1 = fma2(wpb11, h5.hi, aQ1);
        aP0 = fma2(wpa12, h6.lo, aP0);  aP1 = fma2(wpa13, h6.hi, aP1);
        aQ0 = fma2(wpb12, h6.lo, aQ0);  aQ1 = fma2(wpb13, h6.hi, aQ1);
        aP0 = fma2(wpa14, h7.lo, aP0);  aP1 = fma2(wpa15, h7.hi, aP1);
        aQ0 = fma2(wpb14, h7.lo, aQ0);  aQ1 = fma2(wpb15, h7.hi, aQ1);
        const v2f aP = aP0 + aP1;
        const v2f aQ = aQ0 + aQ1;
        const float accA = aP.x + aP.y;   // pre-scaled by -log2e
        const float accB = aQ.x + aQ.y;   // pre-scaled (-2log2e g / -log2e o)

        const float actA = fast_rcp(1.0f + __builtin_exp2f(accA)); // i (lo) / f (hi)
        const float sgB  = fast_rcp(1.0f + __builtin_exp2f(accB));
        const float actB = lo ? fmaf(2.0f, sgB, -1.0f) : sgB;      // g (lo) / o (hi)
        const float oA = xhalf_swap(actA);
        const float oB = xhalf_swap(actB);
        const float gi = lo ? actA : oA;
        const float gf = lo ? oA   : actA;
        const float gg = lo ? actB : oB;
        const float go = lo ? oB   : actB;
        cc = fmaf(gf, cc, gi * gg);
        const float tc = fmaf(2.0f,
            fast_rcp(1.0f + __builtin_exp2f(cc * N2LOG2E)), -1.0f); // tanh(c)
        const float hv = go * tc;

        shc[u * HID + m] = hv;   // staging write == next-step broadcast source
    };

    // ---- prologue: block-0 xg in registers, block-1 indices staged ----
    int xiB0[8], xiB1[8];
    float2 cxg0[8], cxg1[8];
    {
        int xi00[8], xi01[8];
        #pragma unroll
        for (int u = 0; u < 8; ++u) { xi00[u] = x[u * BB + b0]; xi01[u] = x[u * BB + b1]; }
        #pragma unroll
        for (int u = 0; u < 8; ++u) { xiB0[u] = x[(8 + u) * BB + b0]; xiB1[u] = x[(8 + u) * BB + b1]; }
        #pragma unroll
        for (int u = 0; u < 8; ++u) {
            cxg0[u] = tab[(size_t)xi00[u] * 64 + j];
            cxg1[u] = tab[(size_t)xi01[u] * 64 + j];
        }
    }

    for (int t8 = 0; t8 < TT / 8; ++t8) {
        // next-block gathers + next-next-block index loads up front; consumed
        // after the 8 serial step-pairs below -> latency fully hidden.
        float2 nxg0[8], nxg1[8];
        #pragma unroll
        for (int u = 0; u < 8; ++u) {
            nxg0[u] = tab[(size_t)xiB0[u] * 64 + j];
            nxg1[u] = tab[(size_t)xiB1[u] * 64 + j];
        }
        int xiN0[8], xiN1[8];
        const int nb2 = (t8 + 2 < TT / 8) ? (t8 + 2) * 8 : 0;  // tail: dead but safe
        #pragma unroll
        for (int u = 0; u < 8; ++u) {
            xiN0[u] = x[(nb2 + u) * BB + b0];
            xiN1[u] = x[(nb2 + u) * BB + b1];
        }

        #pragma unroll
        for (int u = 0; u < 8; ++u) {
            // two independent chains: scheduler interleaves their DAGs,
            // each fills the other's latency stalls.
            dostep(u, sh0, cxg0[u], c0);
            dostep(u, sh1, cxg1[u], c1);
        }

        // flush 8 steps x 2 chains: coalesced 1KB stores
        const float4 v0 = *(const float4*)(sh0 + j * 4);
        *(float4*)(hrow0 + t8 * 8 * HID + j * 4) = v0;
        const float4 v1 = *(const float4*)(sh1 + j * 4);
        *(float4*)(hrow1 + t8 * 8 * HID + j * 4) = v1;

        // rotate double buffers
        #pragma unroll
        for (int u = 0; u < 8; ++u) {
            cxg0[u] = nxg0[u]; xiB0[u] = xiN0[u];
            cxg1[u] = nxg1[u]; xiB1[u] = xiN1[u];
        }
    }
}

// FF + logits + softmax-over-t, one block per b, 2 timesteps per thread.
__global__ __launch_bounds__(256) void ff_softmax(
    const float* __restrict__ hs,
    const float* __restrict__ W1, const float* __restrict__ b1,
    const float* __restrict__ W2, const float* __restrict__ b2,
    float* __restrict__ out)
{
    const int b    = blockIdx.x;
    const int tid  = threadIdx.x;
    const int lane = tid & 63, wv = tid >> 6;
    const int t0   = tid * 2;

    __shared__ float redM[4][NCLS];
    __shared__ float redS[4][NCLS];

    float4 hv[16];
    const float4* hb = (const float4*)(hs + ((size_t)b * TT + t0) * HID);
    #pragma unroll
    for (int q = 0; q < 16; ++q) hv[q] = hb[q];

    float lg[2][NCLS];
    #pragma unroll
    for (int r = 0; r < 2; ++r) {
        const float* hr = (const float*)(hv + 8 * r);
        float z[FFD];
        #pragma unroll
        for (int f = 0; f < FFD; ++f) {
            float a = b1[f];
            #pragma unroll
            for (int k = 0; k < HID; ++k) a = fmaf(W1[f * HID + k], hr[k], a);
            z[f] = fmaxf(a, 0.f);
        }
        #pragma unroll
        for (int cc = 0; cc < NCLS; ++cc) {
            float a = b2[cc];
            #pragma unroll
            for (int f = 0; f < FFD; ++f) a = fmaf(W2[cc * FFD + f], z[f], a);
            lg[r][cc] = a;
        }
    }

    float M[NCLS], S[NCLS];
    #pragma unroll
    for (int cc = 0; cc < NCLS; ++cc) {
        float mm = fmaxf(lg[0][cc], lg[1][cc]);
        #pragma unroll
        for (int off = 32; off; off >>= 1) mm = fmaxf(mm, __shfl_xor(mm, off));
        if (lane == 0) redM[wv][cc] = mm;
    }
    __syncthreads();
    #pragma unroll
    for (int cc = 0; cc < NCLS; ++cc)
        M[cc] = fmaxf(fmaxf(redM[0][cc], redM[1][cc]), fmaxf(redM[2][cc], redM[3][cc]));

    #pragma unroll
    for (int cc = 0; cc < NCLS; ++cc) {
        float ss = __expf(lg[0][cc] - M[cc]) + __expf(lg[1][cc] - M[cc]);
        #pragma unroll
        for (int off = 32; off; off >>= 1) ss += __shfl_xor(ss, off);
        if (lane == 0) redS[wv][cc] = ss;
    }
    __syncthreads();
    #pragma unroll
    for (int cc = 0; cc < NCLS; ++cc)
        S[cc] = (redS[0][cc] + redS[1][cc]) + (redS[2][cc] + redS[3][cc]);

    #pragma unroll
    for (int r = 0; r < 2; ++r) {
        float* o = out + ((size_t)(t0 + r) * BB + b) * NCLS;
        #pragma unroll
        for (int cc = 0; cc < NCLS; ++cc)
            o[cc] = __expf(lg[r][cc] - M[cc]) * fast_rcp(S[cc]);
    }
}

// ---------------- round-2 verified fused kernel (fallback paths) ----------------
template <bool TAB>
__global__ __launch_bounds__(64) void lstm_all(
    const int* __restrict__ x, const float* __restrict__ emb,
    const float* __restrict__ W_ih, const float* __restrict__ W_hh,
    const float* __restrict__ b_ih, const float* __restrict__ b_hh,
    const float* __restrict__ W1, const float* __restrict__ b1,
    const float* __restrict__ W2, const float* __restrict__ b2,
    const float2* __restrict__ tab, float* __restrict__ out)
{
    const int b  = blockIdx.x;
    const int j  = threadIdx.x;
    const int m  = j & 31;
    const bool lo = j < 32;
    const int rA = j, rB = j + 64;

    float whhA[HID], whhB[HID];
    #pragma unroll
    for (int k = 0; k < HID; k += 4) {
        float4 a;
        a = *(const float4*)(W_hh + rA * HID + k); whhA[k]=a.x; whhA[k+1]=a.y; whhA[k+2]=a.z; whhA[k+3]=a.w;
        a = *(const float4*)(W_hh + rB * HID + k); whhB[k]=a.x; whhB[k+1]=a.y; whhB[k+2]=a.z; whhB[k+3]=a.w;
    }
    float wihA[HID], wihB[HID];
    float biasA = 0.f, biasB = 0.f;
    if constexpr (!TAB) {
        #pragma unroll
        for (int k = 0; k < HID; k += 4) {
            float4 a;
            a = *(const float4*)(W_ih + rA * HID + k); wihA[k]=a.x; wihA[k+1]=a.y; wihA[k+2]=a.z; wihA[k+3]=a.w;
            a = *(const float4*)(W_ih + rB * HID + k); wihB[k]=a.x; wihB[k+1]=a.y; wihB[k+2]=a.z; wihB[k+3]=a.w;
        }
        biasA = b_ih[rA] + b_hh[rA];
        biasB = b_ih[rB] + b_hh[rB];
    }
    const int f16 = j & 15;
    float w1r[HID];
    #pragma unroll
    for (int k = 0; k < HID; ++k) w1r[k] = W1[f16 * HID + k];
    const int cls = j & 7;
    const int c7  = (cls < NCLS) ? cls : 0;
    float w2r[FFD];
    #pragma unroll
    for (int f = 0; f < FFD; ++f) w2r[f] = W2[c7 * FFD + f];
    const float b1v = b1[f16];
    const float b2v = b2[c7];

    float h = 0.f, c = 0.f;
    float mrun = -3.0e38f, srun = 0.f;

    auto gates = [&](float accA, float accB) {
        const float actA = sigf(accA);
        const float sB   = lo ? 2.0f * accB : accB;
        const float sgB  = sigf(sB);
        const float actB = lo ? 2.0f * sgB - 1.0f : sgB;
        const float oA = __shfl_xor(actA, 32);
        const float oB = __shfl_xor(actB, 32);
        const float gi = lo ? actA : oA;
        const float gf = lo ? oA   : actA;
        const float gg = lo ? actB : oB;
        const float go = lo ? oB   : actB;
        c = fmaf(gf, c, gi * gg);
        h = go * tanh_fast(c);
    };

    auto ff_head = [&](int t_out, const float* hsv) {
        float z0 = b1v, z1 = 0.f;
        #pragma unroll
        for (int k = 0; k < HID; k += 2) {
            z0 = fmaf(w1r[k],     hsv[k],     z0);
            z1 = fmaf(w1r[k + 1], hsv[k + 1], z1);
        }
        const float z = fmaxf(z0 + z1, 0.0f);
        float lgv = b2v;
        #pragma unroll
        for (int f = 0; f < FFD; ++f) lgv = fmaf(w2r[f], rl(z, f), lgv);
        const float mn = fmaxf(mrun, lgv);
        srun = fmaf(srun, __expf(mrun - mn), __expf(lgv - mn));
        mrun = mn;
        if (j < NCLS) out[(t_out * BB + b) * NCLS + j] = lgv;
    };

    int xvn1 = x[1 * BB + b];
    int xvn2 = x[2 * BB + b];
    float2 xg = make_float2(0.f, 0.f);
    float eA = 0.f;
    if constexpr (TAB) xg = tab[(size_t)x[b] * 64 + j];
    else               eA = emb[x[b] * EMB + m];

    if constexpr (TAB) {
        gates(xg.x, xg.y);
    } else {
        float es[EMB];
        #pragma unroll
        for (int k = 0; k < EMB; ++k) es[k] = rl(eA, k);
        float p0 = biasA, p1 = 0.f, q0 = biasB, q1 = 0.f;
        #pragma unroll
        for (int k = 0; k < EMB; k += 2) {
            p0 = fmaf(wihA[k],   es[k],   p0); p1 = fmaf(wihA[k+1], es[k+1], p1);
            q0 = fmaf(wihB[k],   es[k],   q0); q1 = fmaf(wihB[k+1], es[k+1], q1);
        }
        gates(p0 + p1, q0 + q1);
    }
    if constexpr (TAB) xg = tab[(size_t)xvn1 * 64 + j];
    else               eA = emb[xvn1 * EMB + m];
    xvn1 = xvn2;
    xvn2 = x[3 * BB + b];

    for (int t = 1; t < TT; ++t) {
        float2 xg_n = make_float2(0.f, 0.f);
        float  e_n  = 0.f;
        if (t + 1 < TT) {
            if constexpr (TAB) xg_n = tab[(size_t)xvn1 * 64 + j];
            else               e_n  = emb[xvn1 * EMB + m];
        }
        const int xv_n3 = (t + 3 < TT) ? x[(t + 3) * BB + b] : 0;

        float hsv[HID];
        #pragma unroll
        for (int k = 0; k < HID; ++k) hsv[k] = rl(h, k);

        ff_head(t - 1, hsv);

        float p0, p1 = 0.f, q0, q1 = 0.f;
        if constexpr (TAB) { p0 = xg.x; q0 = xg.y; }
        else               { p0 = biasA; q0 = biasB; }
        if constexpr (!TAB) {
            float es[EMB];
            #pragma unroll
            for (int k = 0; k < EMB; ++k) es[k] = rl(eA, k);
            #pragma unroll
            for (int k = 0; k < EMB; k += 2) {
                p0 = fmaf(wihA[k],   es[k],   p0); p1 = fmaf(wihA[k+1], es[k+1], p1);
                q0 = fmaf(wihB[k],   es[k],   q0); q1 = fmaf(wihB[k+1], es[k+1], q1);
            }
        }
        #pragma unroll
        for (int k = 0; k < HID; k += 2) {
            p0 = fmaf(whhA[k],   hsv[k],   p0); p1 = fmaf(whhA[k+1], hsv[k+1], p1);
            q0 = fmaf(whhB[k],   hsv[k],   q0); q1 = fmaf(whhB[k+1], hsv[k+1], q1);
        }
        gates(p0 + p1, q0 + q1);

        xg = xg_n; eA = e_n; xvn1 = xvn2; xvn2 = xv_n3;
    }

    {
        float hsv[HID];
        #pragma unroll
        for (int k = 0; k < HID; ++k) hsv[k] = rl(h, k);
        ff_head(TT - 1, hsv);
    }

    #pragma unroll 1
    for (int cc = 0; cc < NCLS; ++cc) {
        const float mc = rl(mrun, cc);
        const float sc = rl(srun, cc);
        const float ic = 1.0f / sc;
        #pragma unroll
        for (int i = 0; i < TT / 64; ++i) {
            const int t = j + 64 * i;
            const int a = (t * BB + b) * NCLS + cc;
            out[a] = __expf(out[a] - mc) * ic;
        }
    }
}

extern "C" void kernel_launch(void* const* d_in, const int* in_sizes, int n_in,
                              void* d_out, int out_size, void* d_ws, size_t ws_size,
                              hipStream_t stream) {
    const int*   x   = (const int*)  d_in[0];
    const float* emb = (const float*)d_in[1];
    const float* Wih = (const float*)d_in[2];
    const float* Whh = (const float*)d_in[3];
    const float* bih = (const float*)d_in[4];
    const float* bhh = (const float*)d_in[5];
    const float* W1  = (const float*)d_in[6];
    const float* b1  = (const float*)d_in[7];
    const float* W2  = (const float*)d_in[8];
    const float* b2  = (const float*)d_in[9];
    float* out = (float*)d_out;

    const size_t tab_bytes = (size_t)VOCABN * 128 * sizeof(float);   // 512 000
    const size_t hs_off    = 524288;                                 // 512 KiB align
    const size_t hs_bytes  = (size_t)BB * TT * HID * sizeof(float);  // 32 MiB
    if (ws_size >= hs_off + hs_bytes) {
        float2* tab = (float2*)d_ws;
        float*  hs  = (float*)((char*)d_ws + hs_off);
        build_xg<<<VOCABN, 64, 0, stream>>>(emb, Wih, bih, bhh, tab, 1);
        lstm_rec2<<<BB / 2, 64, 0, stream>>>(x, tab, Whh, hs);
        ff_softmax<<<BB, 256, 0, stream>>>(hs, W1, b1, W2, b2, out);
    } else if (ws_size >= tab_bytes) {
        float2* tab = (float2*)d_ws;
        build_xg<<<VOCABN, 64, 0, stream>>>(emb, Wih, bih, bhh, tab, 0);
        lstm_all<true><<<BB, 64, 0, stream>>>(x, emb, Wih, Whh, bih, bhh,
                                              W1, b1, W2, b2, tab, out);
    } else {
        lstm_all<false><<<BB, 64, 0, stream>>>(x, emb, Wih, Whh, bih, bhh,
                                               W1, b1, W2, b2, nullptr, out);
    }
}

// Round 7
// 287.348 us; speedup vs baseline: 1.2466x; 1.2466x over previous
//
#include <hip/hip_runtime.h>
#include <math.h>

#define TT    512
#define BB    512
#define HID   32
#define EMB   32
#define FFD   16
#define NCLS  7
#define VOCABN 1000

typedef float v2f __attribute__((ext_vector_type(2)));
typedef float v4f __attribute__((ext_vector_type(4)));

#define NLOG2E  (-1.4426950408889634f)
#define N2LOG2E (-2.8853900817779268f)

__device__ __forceinline__ float rl(float v, int k) {
    return __int_as_float(__builtin_amdgcn_readlane(__float_as_int(v), k));
}
__device__ __forceinline__ float fast_rcp(float x) {
#if defined(__has_builtin)
#if __has_builtin(__builtin_amdgcn_rcpf)
    return __builtin_amdgcn_rcpf(x);
#else
    return 1.0f / x;
#endif
#else
    return 1.0f / x;
#endif
}
__device__ __forceinline__ float sigf(float x) { return fast_rcp(1.0f + __expf(-x)); }
__device__ __forceinline__ float tanh_fast(float x) { return 2.0f * sigf(2.0f * x) - 1.0f; }

__device__ __forceinline__ v2f fma2(v2f a, v2f b, v2f c) {
#if defined(__has_builtin)
#if __has_builtin(__builtin_elementwise_fma)
    return __builtin_elementwise_fma(a, b, c);
#else
    v2f r; r.x = fmaf(a.x, b.x, c.x); r.y = fmaf(a.y, b.y, c.y); return r;
#endif
#else
    v2f r; r.x = fmaf(a.x, b.x, c.x); r.y = fmaf(a.y, b.y, c.y); return r;
#endif
}

// Cross-half (lane ^ 32) exchange via v_permlane32_swap_b32 (VALU).
// Orientation-proof: r[0]^r[1]^self == partner.
__device__ __forceinline__ float xhalf_swap(float v) {
#if defined(__has_builtin)
#if __has_builtin(__builtin_amdgcn_permlane32_swap)
    const unsigned u = __float_as_uint(v);
    auto r = __builtin_amdgcn_permlane32_swap(u, u, false, false);
    return __uint_as_float((r[0] ^ r[1]) ^ u);
#else
    return __shfl_xor(v, 32);
#endif
#else
    return __shfl_xor(v, 32);
#endif
}

// lane-xor exchanges for the butterfly broadcast
#define SWZF(x, imm) __int_as_float(__builtin_amdgcn_ds_swizzle(__float_as_int(x), (imm)))
#if defined(__has_builtin)
#if __has_builtin(__builtin_amdgcn_mov_dpp)
#define XOR1F(x) __int_as_float(__builtin_amdgcn_mov_dpp(__float_as_int(x), 0xB1, 0xF, 0xF, true)) /* quad_perm [1,0,3,2] */
#define XOR2F(x) __int_as_float(__builtin_amdgcn_mov_dpp(__float_as_int(x), 0x4E, 0xF, 0xF, true)) /* quad_perm [2,3,0,1] */
#else
#define XOR1F(x) SWZF(x, 0x041F)
#define XOR2F(x) SWZF(x, 0x081F)
#endif
#else
#define XOR1F(x) SWZF(x, 0x041F)
#define XOR2F(x) SWZF(x, 0x081F)
#endif

// xg_table[v][j] = {W_ih[j,:]·emb[v,:]+b[j], W_ih[j+64,:]·emb[v,:]+b[j+64]}
// scaled!=0: entries pre-multiplied by the activation log2-scales (see lstm_rec).
__global__ __launch_bounds__(64) void build_xg(
    const float* __restrict__ emb, const float* __restrict__ W_ih,
    const float* __restrict__ b_ih, const float* __restrict__ b_hh,
    float2* __restrict__ tab, int scaled)
{
    const int v = blockIdx.x;
    const int j = threadIdx.x;
    const float* e  = emb + v * EMB;
    const float* w0 = W_ih + j * EMB;
    const float* w1 = W_ih + (j + 64) * EMB;
    float a0 = b_ih[j]      + b_hh[j];
    float a1 = b_ih[j + 64] + b_hh[j + 64];
    #pragma unroll
    for (int k = 0; k < EMB; ++k) {
        const float ek = e[k];
        a0 = fmaf(w0[k], ek, a0);
        a1 = fmaf(w1[k], ek, a1);
    }
    float s0 = 1.0f, s1 = 1.0f;
    if (scaled) { s0 = NLOG2E; s1 = (j < 32) ? N2LOG2E : NLOG2E; }
    tab[v * 64 + j] = make_float2(a0 * s0, a1 * s1);
}

// Serial recurrence. One wave per chain (latency-bound).
// R6 EVIDENCE: 2 chains/wave ran SERIAL (pair=1247 ~ 2x689 cyc) -> packing
// cannot shorten the dependence chain; only the per-step critical path can.
// R5 path: ds_write(h) -> ds_read_b128 x8 -> lgkmcnt drain ~ 150-250 cyc of
// the 689-cyc step. THIS version replaces the LDS round trip with a 5-level
// in-register butterfly broadcast (xor4/8/16 via ds_swizzle, xor1/2 via DPP;
// depth ~3 swizzles+2 DPP ~ 100cyc, early levels feed the FMA chains while
// late levels finish). The induced lane permutation sigma is absorbed into
// the WEIGHT LOAD ORDER (lane j reg k holds h[m^sigma(k)]; load W[r][m^sigma(k)]).
// LDS is deleted entirely: h goes straight to global (128B coalesced store,
// fire-and-forget, off the critical path; upper-half duplicate writes benign).
__global__ __launch_bounds__(64)
__attribute__((amdgpu_waves_per_eu(1, 1)))
void lstm_rec(
    const int* __restrict__ x, const float2* __restrict__ tab,
    const float* __restrict__ W_hh, float* __restrict__ hsout)
{
    const int b  = blockIdx.x;
    const int j  = threadIdx.x;
    const int m  = j & 31;
    const bool lo = j < 32;

    // ---- W_hh rows j, j+64 -> 32 named v2f pairs, sigma-permuted, pre-scaled ----
    // sigma(k) = 4*b0 + 8*b1 + 16*b2 + 1*b3 + 2*b4 (butterfly level order 4,8,16,1,2)
    const float fA = NLOG2E;
    const float fB = lo ? N2LOG2E : NLOG2E;
    const v2f sA2 = {fA, fA};
    const v2f sB2 = {fB, fB};
    const float* WrA = W_hh + (size_t)j * HID;
    const float* WrB = W_hh + (size_t)(j + 64) * HID;
    v2f wpa0,wpa1,wpa2,wpa3,wpa4,wpa5,wpa6,wpa7,wpa8,wpa9,wpa10,wpa11,wpa12,wpa13,wpa14,wpa15;
    v2f wpb0,wpb1,wpb2,wpb3,wpb4,wpb5,wpb6,wpb7,wpb8,wpb9,wpb10,wpb11,wpb12,wpb13,wpb14,wpb15;
    #define LDW(t, s0, s1) \
        wpa##t = (v2f){WrA[m ^ (s0)], WrA[m ^ (s1)]} * sA2; \
        wpb##t = (v2f){WrB[m ^ (s0)], WrB[m ^ (s1)]} * sB2;
    LDW(0,  0,  4)  LDW(1,  8, 12)  LDW(2, 16, 20)  LDW(3, 24, 28)
    LDW(4,  1,  5)  LDW(5,  9, 13)  LDW(6, 17, 21)  LDW(7, 25, 29)
    LDW(8,  2,  6)  LDW(9, 10, 14)  LDW(10,18, 22)  LDW(11,26, 30)
    LDW(12, 3,  7)  LDW(13,11, 15)  LDW(14,19, 23)  LDW(15,27, 31)
    #undef LDW

    float h = 0.f, c = 0.f;
    float* hrow0 = hsout + (size_t)b * TT * HID;

    // ---- prologue: block-0 xg in registers, block-1 indices staged ----
    int xiB[8];
    float2 cxg[8];
    {
        int xi0[8];
        #pragma unroll
        for (int u = 0; u < 8; ++u) xi0[u] = x[u * BB + b];
        #pragma unroll
        for (int u = 0; u < 8; ++u) xiB[u] = x[(8 + u) * BB + b];
        #pragma unroll
        for (int u = 0; u < 8; ++u) cxg[u] = tab[(size_t)xi0[u] * 64 + j];
    }

    for (int t8 = 0; t8 < TT / 8; ++t8) {
        // next-block gathers + next-next-block index loads up front;
        // consumed after the 8 serial steps below -> latency fully hidden.
        float2 nxg[8];
        #pragma unroll
        for (int u = 0; u < 8; ++u) nxg[u] = tab[(size_t)xiB[u] * 64 + j];
        int xiN[8];
        const int nb2 = (t8 + 2 < TT / 8) ? (t8 + 2) * 8 : 0;  // tail: dead but safe
        #pragma unroll
        for (int u = 0; u < 8; ++u) xiN[u] = x[(nb2 + u) * BB + b];

        #pragma unroll
        for (int u = 0; u < 8; ++u) {
            // ---- butterfly broadcast: lane j reg k ends with h[m ^ sigma(k)] ----
            const float u0 = h;
            const float u1 = SWZF(u0, 0x101F);                       // ^4
            const float u2 = SWZF(u0, 0x201F);                       // ^8
            const float u3 = SWZF(u1, 0x201F);
            const float u4 = SWZF(u0, 0x401F);                       // ^16
            const float u5 = SWZF(u1, 0x401F);
            const float u6 = SWZF(u2, 0x401F);
            const float u7 = SWZF(u3, 0x401F);
            const float u8  = XOR1F(u0),  u9  = XOR1F(u1);           // ^1
            const float u10 = XOR1F(u2),  u11 = XOR1F(u3);
            const float u12 = XOR1F(u4),  u13 = XOR1F(u5);
            const float u14 = XOR1F(u6),  u15 = XOR1F(u7);
            const float u16 = XOR2F(u0),  u17 = XOR2F(u1);           // ^2
            const float u18 = XOR2F(u2),  u19 = XOR2F(u3);
            const float u20 = XOR2F(u4),  u21 = XOR2F(u5);
            const float u22 = XOR2F(u6),  u23 = XOR2F(u7);
            const float u24 = XOR2F(u8),  u25 = XOR2F(u9);
            const float u26 = XOR2F(u10), u27 = XOR2F(u11);
            const float u28 = XOR2F(u12), u29 = XOR2F(u13);
            const float u30 = XOR2F(u14), u31 = XOR2F(u15);
            const v2f hp0  = {u0,  u1},  hp1  = {u2,  u3};
            const v2f hp2  = {u4,  u5},  hp3  = {u6,  u7};
            const v2f hp4  = {u8,  u9},  hp5  = {u10, u11};
            const v2f hp6  = {u12, u13}, hp7  = {u14, u15};
            const v2f hp8  = {u16, u17}, hp9  = {u18, u19};
            const v2f hp10 = {u20, u21}, hp11 = {u22, u23};
            const v2f hp12 = {u24, u25}, hp13 = {u26, u27};
            const v2f hp14 = {u28, u29}, hp15 = {u30, u31};

            // dot: 32 pk_fma, 4 chains, ordered by operand readiness
            v2f aP0 = {cxg[u].x, 0.f}, aP1 = {0.f, 0.f};
            v2f aQ0 = {cxg[u].y, 0.f}, aQ1 = {0.f, 0.f};
            aP0 = fma2(wpa0,  hp0,  aP0);  aQ0 = fma2(wpb0,  hp0,  aQ0);
            aP1 = fma2(wpa4,  hp4,  aP1);  aQ1 = fma2(wpb4,  hp4,  aQ1);
            aP0 = fma2(wpa8,  hp8,  aP0);  aQ0 = fma2(wpb8,  hp8,  aQ0);
            aP1 = fma2(wpa12, hp12, aP1);  aQ1 = fma2(wpb12, hp12, aQ1);
            aP0 = fma2(wpa1,  hp1,  aP0);  aQ0 = fma2(wpb1,  hp1,  aQ0);
            aP1 = fma2(wpa2,  hp2,  aP1);  aQ1 = fma2(wpb2,  hp2,  aQ1);
            aP0 = fma2(wpa5,  hp5,  aP0);  aQ0 = fma2(wpb5,  hp5,  aQ0);
            aP1 = fma2(wpa6,  hp6,  aP1);  aQ1 = fma2(wpb6,  hp6,  aQ1);
            aP0 = fma2(wpa9,  hp9,  aP0);  aQ0 = fma2(wpb9,  hp9,  aQ0);
            aP1 = fma2(wpa10, hp10, aP1);  aQ1 = fma2(wpb10, hp10, aQ1);
            aP0 = fma2(wpa13, hp13, aP0);  aQ0 = fma2(wpb13, hp13, aQ0);
            aP1 = fma2(wpa14, hp14, aP1);  aQ1 = fma2(wpb14, hp14, aQ1);
            aP0 = fma2(wpa3,  hp3,  aP0);  aQ0 = fma2(wpb3,  hp3,  aQ0);
            aP1 = fma2(wpa7,  hp7,  aP1);  aQ1 = fma2(wpb7,  hp7,  aQ1);
            aP0 = fma2(wpa11, hp11, aP0);  aQ0 = fma2(wpb11, hp11, aQ0);
            aP1 = fma2(wpa15, hp15, aP1);  aQ1 = fma2(wpb15, hp15, aQ1);
            const v2f aP = aP0 + aP1;
            const v2f aQ = aQ0 + aQ1;
            const float accA = aP.x + aP.y;   // pre-scaled by -log2e
            const float accB = aQ.x + aQ.y;   // pre-scaled (-2log2e g / -log2e o)

            // sigmoid/tanh in exp2 form (scales folded into acc)
            const float actA = fast_rcp(1.0f + __builtin_exp2f(accA)); // i (lo) / f (hi)
            const float sgB  = fast_rcp(1.0f + __builtin_exp2f(accB));
            const float actB = lo ? fmaf(2.0f, sgB, -1.0f) : sgB;      // g (lo) / o (hi)
            const float oA = xhalf_swap(actA);
            const float oB = xhalf_swap(actB);
            const float gi = lo ? actA : oA;
            const float gf = lo ? oA   : actA;
            const float gg = lo ? actB : oB;
            const float go = lo ? oB   : actB;
            c = fmaf(gf, c, gi * gg);
            const float tc = fmaf(2.0f,
                fast_rcp(1.0f + __builtin_exp2f(c * N2LOG2E)), -1.0f); // tanh(c)
            h = go * tc;

            // direct global store: 128B coalesced (lanes 32-63 write the same
            // addresses with identical values - benign), fire-and-forget.
            hrow0[(t8 * 8 + u) * HID + m] = h;
        }

        // rotate double buffers
        #pragma unroll
        for (int u = 0; u < 8; ++u) { cxg[u] = nxg[u]; xiB[u] = xiN[u]; }
    }
}

// FF + logits + softmax-over-t, one block per b, 2 timesteps per thread.
__global__ __launch_bounds__(256) void ff_softmax(
    const float* __restrict__ hs,
    const float* __restrict__ W1, const float* __restrict__ b1,
    const float* __restrict__ W2, const float* __restrict__ b2,
    float* __restrict__ out)
{
    const int b    = blockIdx.x;
    const int tid  = threadIdx.x;
    const int lane = tid & 63, wv = tid >> 6;
    const int t0   = tid * 2;

    __shared__ float redM[4][NCLS];
    __shared__ float redS[4][NCLS];

    float4 hv[16];
    const float4* hb = (const float4*)(hs + ((size_t)b * TT + t0) * HID);
    #pragma unroll
    for (int q = 0; q < 16; ++q) hv[q] = hb[q];

    float lg[2][NCLS];
    #pragma unroll
    for (int r = 0; r < 2; ++r) {
        const float* hr = (const float*)(hv + 8 * r);
        float z[FFD];
        #pragma unroll
        for (int f = 0; f < FFD; ++f) {
            float a = b1[f];
            #pragma unroll
            for (int k = 0; k < HID; ++k) a = fmaf(W1[f * HID + k], hr[k], a);
            z[f] = fmaxf(a, 0.f);
        }
        #pragma unroll
        for (int cc = 0; cc < NCLS; ++cc) {
            float a = b2[cc];
            #pragma unroll
            for (int f = 0; f < FFD; ++f) a = fmaf(W2[cc * FFD + f], z[f], a);
            lg[r][cc] = a;
        }
    }

    float M[NCLS], S[NCLS];
    #pragma unroll
    for (int cc = 0; cc < NCLS; ++cc) {
        float mm = fmaxf(lg[0][cc], lg[1][cc]);
        #pragma unroll
        for (int off = 32; off; off >>= 1) mm = fmaxf(mm, __shfl_xor(mm, off));
        if (lane == 0) redM[wv][cc] = mm;
    }
    __syncthreads();
    #pragma unroll
    for (int cc = 0; cc < NCLS; ++cc)
        M[cc] = fmaxf(fmaxf(redM[0][cc], redM[1][cc]), fmaxf(redM[2][cc], redM[3][cc]));

    #pragma unroll
    for (int cc = 0; cc < NCLS; ++cc) {
        float ss = __expf(lg[0][cc] - M[cc]) + __expf(lg[1][cc] - M[cc]);
        #pragma unroll
        for (int off = 32; off; off >>= 1) ss += __shfl_xor(ss, off);
        if (lane == 0) redS[wv][cc] = ss;
    }
    __syncthreads();
    #pragma unroll
    for (int cc = 0; cc < NCLS; ++cc)
        S[cc] = (redS[0][cc] + redS[1][cc]) + (redS[2][cc] + redS[3][cc]);

    #pragma unroll
    for (int r = 0; r < 2; ++r) {
        float* o = out + ((size_t)(t0 + r) * BB + b) * NCLS;
        #pragma unroll
        for (int cc = 0; cc < NCLS; ++cc)
            o[cc] = __expf(lg[r][cc] - M[cc]) * fast_rcp(S[cc]);
    }
}

// ---------------- round-2 verified fused kernel (fallback paths) ----------------
template <bool TAB>
__global__ __launch_bounds__(64) void lstm_all(
    const int* __restrict__ x, const float* __restrict__ emb,
    const float* __restrict__ W_ih, const float* __restrict__ W_hh,
    const float* __restrict__ b_ih, const float* __restrict__ b_hh,
    const float* __restrict__ W1, const float* __restrict__ b1,
    const float* __restrict__ W2, const float* __restrict__ b2,
    const float2* __restrict__ tab, float* __restrict__ out)
{
    const int b  = blockIdx.x;
    const int j  = threadIdx.x;
    const int m  = j & 31;
    const bool lo = j < 32;
    const int rA = j, rB = j + 64;

    float whhA[HID], whhB[HID];
    #pragma unroll
    for (int k = 0; k < HID; k += 4) {
        float4 a;
        a = *(const float4*)(W_hh + rA * HID + k); whhA[k]=a.x; whhA[k+1]=a.y; whhA[k+2]=a.z; whhA[k+3]=a.w;
        a = *(const float4*)(W_hh + rB * HID + k); whhB[k]=a.x; whhB[k+1]=a.y; whhB[k+2]=a.z; whhB[k+3]=a.w;
    }
    float wihA[HID], wihB[HID];
    float biasA = 0.f, biasB = 0.f;
    if constexpr (!TAB) {
        #pragma unroll
        for (int k = 0; k < HID; k += 4) {
            float4 a;
            a = *(const float4*)(W_ih + rA * HID + k); wihA[k]=a.x; wihA[k+1]=a.y; wihA[k+2]=a.z; wihA[k+3]=a.w;
            a = *(const float4*)(W_ih + rB * HID + k); wihB[k]=a.x; wihB[k+1]=a.y; wihB[k+2]=a.z; wihB[k+3]=a.w;
        }
        biasA = b_ih[rA] + b_hh[rA];
        biasB = b_ih[rB] + b_hh[rB];
    }
    const int f16 = j & 15;
    float w1r[HID];
    #pragma unroll
    for (int k = 0; k < HID; ++k) w1r[k] = W1[f16 * HID + k];
    const int cls = j & 7;
    const int c7  = (cls < NCLS) ? cls : 0;
    float w2r[FFD];
    #pragma unroll
    for (int f = 0; f < FFD; ++f) w2r[f] = W2[c7 * FFD + f];
    const float b1v = b1[f16];
    const float b2v = b2[c7];

    float h = 0.f, c = 0.f;
    float mrun = -3.0e38f, srun = 0.f;

    auto gates = [&](float accA, float accB) {
        const float actA = sigf(accA);
        const float sB   = lo ? 2.0f * accB : accB;
        const float sgB  = sigf(sB);
        const float actB = lo ? 2.0f * sgB - 1.0f : sgB;
        const float oA = __shfl_xor(actA, 32);
        const float oB = __shfl_xor(actB, 32);
        const float gi = lo ? actA : oA;
        const float gf = lo ? oA   : actA;
        const float gg = lo ? actB : oB;
        const float go = lo ? oB   : actB;
        c = fmaf(gf, c, gi * gg);
        h = go * tanh_fast(c);
    };

    auto ff_head = [&](int t_out, const float* hsv) {
        float z0 = b1v, z1 = 0.f;
        #pragma unroll
        for (int k = 0; k < HID; k += 2) {
            z0 = fmaf(w1r[k],     hsv[k],     z0);
            z1 = fmaf(w1r[k + 1], hsv[k + 1], z1);
        }
        const float z = fmaxf(z0 + z1, 0.0f);
        float lgv = b2v;
        #pragma unroll
        for (int f = 0; f < FFD; ++f) lgv = fmaf(w2r[f], rl(z, f), lgv);
        const float mn = fmaxf(mrun, lgv);
        srun = fmaf(srun, __expf(mrun - mn), __expf(lgv - mn));
        mrun = mn;
        if (j < NCLS) out[(t_out * BB + b) * NCLS + j] = lgv;
    };

    int xvn1 = x[1 * BB + b];
    int xvn2 = x[2 * BB + b];
    float2 xg = make_float2(0.f, 0.f);
    float eA = 0.f;
    if constexpr (TAB) xg = tab[(size_t)x[b] * 64 + j];
    else               eA = emb[x[b] * EMB + m];

    if constexpr (TAB) {
        gates(xg.x, xg.y);
    } else {
        float es[EMB];
        #pragma unroll
        for (int k = 0; k < EMB; ++k) es[k] = rl(eA, k);
        float p0 = biasA, p1 = 0.f, q0 = biasB, q1 = 0.f;
        #pragma unroll
        for (int k = 0; k < EMB; k += 2) {
            p0 = fmaf(wihA[k],   es[k],   p0); p1 = fmaf(wihA[k+1], es[k+1], p1);
            q0 = fmaf(wihB[k],   es[k],   q0); q1 = fmaf(wihB[k+1], es[k+1], q1);
        }
        gates(p0 + p1, q0 + q1);
    }
    if constexpr (TAB) xg = tab[(size_t)xvn1 * 64 + j];
    else               eA = emb[xvn1 * EMB + m];
    xvn1 = xvn2;
    xvn2 = x[3 * BB + b];

    for (int t = 1; t < TT; ++t) {
        float2 xg_n = make_float2(0.f, 0.f);
        float  e_n  = 0.f;
        if (t + 1 < TT) {
            if constexpr (TAB) xg_n = tab[(size_t)xvn1 * 64 + j];
            else               e_n  = emb[xvn1 * EMB + m];
        }
        const int xv_n3 = (t + 3 < TT) ? x[(t + 3) * BB + b] : 0;

        float hsv[HID];
        #pragma unroll
        for (int k = 0; k < HID; ++k) hsv[k] = rl(h, k);

        ff_head(t - 1, hsv);

        float p0, p1 = 0.f, q0, q1 = 0.f;
        if constexpr (TAB) { p0 = xg.x; q0 = xg.y; }
        else               { p0 = biasA; q0 = biasB; }
        if constexpr (!TAB) {
            float es[EMB];
            #pragma unroll
            for (int k = 0; k < EMB; ++k) es[k] = rl(eA, k);
            #pragma unroll
            for (int k = 0; k < EMB; k += 2) {
                p0 = fmaf(wihA[k],   es[k],   p0); p1 = fmaf(wihA[k+1], es[k+1], p1);
                q0 = fmaf(wihB[k],   es[k],   q0); q1 = fmaf(wihB[k+1], es[k+1], q1);
            }
        }
        #pragma unroll
        for (int k = 0; k < HID; k += 2) {
            p0 = fmaf(whhA[k],   hsv[k],   p0); p1 = fmaf(whhA[k+1], hsv[k+1], p1);
            q0 = fmaf(whhB[k],   hsv[k],   q0); q1 = fmaf(whhB[k+1], hsv[k+1], q1);
        }
        gates(p0 + p1, q0 + q1);

        xg = xg_n; eA = e_n; xvn1 = xvn2; xvn2 = xv_n3;
    }

    {
        float hsv[HID];
        #pragma unroll
        for (int k = 0; k < HID; ++k) hsv[k] = rl(h, k);
        ff_head(TT - 1, hsv);
    }

    #pragma unroll 1
    for (int cc = 0; cc < NCLS; ++cc) {
        const float mc = rl(mrun, cc);
        const float sc = rl(srun, cc);
        const float ic = 1.0f / sc;
        #pragma unroll
        for (int i = 0; i < TT / 64; ++i) {
            const int t = j + 64 * i;
            const int a = (t * BB + b) * NCLS + cc;
            out[a] = __expf(out[a] - mc) * ic;
        }
    }
}

extern "C" void kernel_launch(void* const* d_in, const int* in_sizes, int n_in,
                              void* d_out, int out_size, void* d_ws, size_t ws_size,
                              hipStream_t stream) {
    const int*   x   = (const int*)  d_in[0];
    const float* emb = (const float*)d_in[1];
    const float* Wih = (const float*)d_in[2];
    const float* Whh = (const float*)d_in[3];
    const float* bih = (const float*)d_in[4];
    const float* bhh = (const float*)d_in[5];
    const float* W1  = (const float*)d_in[6];
    const float* b1  = (const float*)d_in[7];
    const float* W2  = (const float*)d_in[8];
    const float* b2  = (const float*)d_in[9];
    float* out = (float*)d_out;

    const size_t tab_bytes = (size_t)VOCABN * 128 * sizeof(float);   // 512 000
    const size_t hs_off    = 524288;                                 // 512 KiB align
    const size_t hs_bytes  = (size_t)BB * TT * HID * sizeof(float);  // 32 MiB
    if (ws_size >= hs_off + hs_bytes) {
        float2* tab = (float2*)d_ws;
        float*  hs  = (float*)((char*)d_ws + hs_off);
        build_xg<<<VOCABN, 64, 0, stream>>>(emb, Wih, bih, bhh, tab, 1);
        lstm_rec<<<BB, 64, 0, stream>>>(x, tab, Whh, hs);
        ff_softmax<<<BB, 256, 0, stream>>>(hs, W1, b1, W2, b2, out);
    } else if (ws_size >= tab_bytes) {
        float2* tab = (float2*)d_ws;
        build_xg<<<VOCABN, 64, 0, stream>>>(emb, Wih, bih, bhh, tab, 0);
        lstm_all<true><<<BB, 64, 0, stream>>>(x, emb, Wih, Whh, bih, bhh,
                                              W1, b1, W2, b2, tab, out);
    } else {
        lstm_all<false><<<BB, 64, 0, stream>>>(x, emb, Wih, Whh, bih, bhh,
                                               W1, b1, W2, b2, nullptr, out);
    }
}